// Round 1
// baseline (10319.580 us; speedup 1.0000x reference)
//
#include <hip/hip_runtime.h>
#include <hip/hip_bf16.h>
#include <stdint.h>

// Problem dims (fixed by reference)
#define B_   16
#define T_   512
#define V_   8192
#define E_   512
#define H_   1024
#define BT_  (B_ * T_)   // 8192 rows, row r = b*T + t
#define H4_  (4 * H_)    // 4096

typedef __attribute__((ext_vector_type(8))) short   short8;
typedef __attribute__((ext_vector_type(8))) __bf16  bf16x8;
typedef __attribute__((ext_vector_type(4))) float   f32x4;
typedef __attribute__((ext_vector_type(4))) short   short4v;

__device__ __forceinline__ float bf2f(short s) {
  union { unsigned u; float f; } x;
  x.u = ((unsigned)(unsigned short)s) << 16;
  return x.f;
}
__device__ __forceinline__ short f2bf(float f) {
  union { float f; unsigned u; } x; x.f = f;
  unsigned u = x.u;
  u = (u + 0x7fffu + ((u >> 16) & 1u)) >> 16;   // RNE
  return (short)u;
}
__device__ __forceinline__ f32x4 mfma16(short8 a, short8 b, f32x4 c) {
  return __builtin_amdgcn_mfma_f32_16x16x32_bf16(
      __builtin_bit_cast(bf16x8, a), __builtin_bit_cast(bf16x8, b), c, 0, 0, 0);
}
__device__ __forceinline__ float sigm(float x) { return 1.f / (1.f + __expf(-x)); }
__device__ __forceinline__ float tanh_f(float x) { return 1.f - 2.f / (__expf(2.f * x) + 1.f); }

// ---------------------------------------------------------------------------
// 1) column L2-norm scales: sc[j] = g[j] / max(||W[:,j]||, 1e-12)
__global__ __launch_bounds__(256) void colscale(const float* __restrict__ W,
                                                const float* __restrict__ g,
                                                float* __restrict__ sc, int Kr, int N) {
  int j = blockIdx.x * 256 + threadIdx.x;
  if (j >= N) return;
  float ss = 0.f;
  for (int i = 0; i < Kr; ++i) { float v = W[(long)i * N + j]; ss = fmaf(v, v, ss); }
  sc[j] = g[j] / fmaxf(sqrtf(ss), 1e-12f);
}

// 2) WT[j][i] = bf16(W[i][j] * sc[j]) — LDS 32x32 tile transpose, coalesced both sides
__global__ __launch_bounds__(256) void transpose_cast(const float* __restrict__ W,
                                                      const float* __restrict__ sc,
                                                      short* __restrict__ WT, int Kr, int N) {
  __shared__ float tile[32][33];
  int nbi = Kr >> 5;
  int bi = blockIdx.x % nbi, bj = blockIdx.x / nbi;
  int i0 = bi << 5, j0 = bj << 5;
  int tx = threadIdx.x & 31, ty = threadIdx.x >> 5;   // 32 x 8
  for (int yy = ty; yy < 32; yy += 8)
    tile[yy][tx] = W[(long)(i0 + yy) * N + j0 + tx];
  __syncthreads();
  for (int yy = ty; yy < 32; yy += 8) {
    int j = j0 + yy;
    WT[(long)j * Kr + i0 + tx] = f2bf(tile[tx][yy] * sc[j]);
  }
}

// 3) plain f32 -> bf16 cast (pred_w is already [V][K] layout)
__global__ __launch_bounds__(256) void castbf(const float* __restrict__ src,
                                              short* __restrict__ dst, long n) {
  long i = ((long)blockIdx.x * 256 + threadIdx.x) * 4;
  if (i + 3 < n) {
    float4 v = *(const float4*)(src + i);
    short4v o = { f2bf(v.x), f2bf(v.y), f2bf(v.z), f2bf(v.w) };
    *(short4v*)(dst + i) = o;
  }
}

// 4) embedding gather with padding_idx=0 -> zeros
__global__ __launch_bounds__(256) void embed_gather(const int* __restrict__ xs,
                                                    const float* __restrict__ ew,
                                                    short* __restrict__ x) {
  int r = blockIdx.x;
  int idx = xs[r];
  const float* src = ew + (long)idx * E_;
  for (int e = threadIdx.x; e < E_; e += 256) {
    float v = (idx == 0) ? 0.f : src[e];
    x[(long)r * E_ + e] = f2bf(v);
  }
}

// ---------------------------------------------------------------------------
// Generic 128x128-tile bf16 MFMA GEMM: C[M][N](bf16) = A[M][K] @ BT[N][K]^T (+bias)
// 4 waves, each owns a 64x64 quadrant = 4x4 16x16 frags. Fragments from global.
__global__ __launch_bounds__(256) void gemm_bt(const short* __restrict__ A,
                                               const short* __restrict__ BT,
                                               const float* __restrict__ bias,
                                               short* __restrict__ C,
                                               int M, int N, int K) {
  int ntiles = N >> 7;
  int tM = (blockIdx.x / ntiles) << 7;
  int tN = (blockIdx.x % ntiles) << 7;
  int w = threadIdx.x >> 6, lane = threadIdx.x & 63;
  int mo = tM + ((w & 1) << 6), no = tN + ((w >> 1) << 6);
  int lr = lane & 15, lk8 = (lane >> 4) << 3, q = lane >> 4;
  f32x4 acc[4][4] = {};
  const short* Ap = A + (long)(mo + lr) * K + lk8;
  const short* Bp = BT + (long)(no + lr) * K + lk8;
  for (int k0 = 0; k0 < K; k0 += 32) {
    short8 af[4], bfr[4];
#pragma unroll
    for (int i = 0; i < 4; ++i) af[i] = *(const short8*)(Ap + (long)16 * i * K + k0);
#pragma unroll
    for (int j = 0; j < 4; ++j) bfr[j] = *(const short8*)(Bp + (long)16 * j * K + k0);
#pragma unroll
    for (int i = 0; i < 4; ++i)
#pragma unroll
      for (int j = 0; j < 4; ++j)
        acc[i][j] = mfma16(af[i], bfr[j], acc[i][j]);
  }
  float pbv[4];
#pragma unroll
  for (int j = 0; j < 4; ++j) pbv[j] = bias ? bias[no + 16 * j + lr] : 0.f;
#pragma unroll
  for (int i = 0; i < 4; ++i)
#pragma unroll
    for (int j = 0; j < 4; ++j)
#pragma unroll
      for (int r = 0; r < 4; ++r) {
        int row = mo + 16 * i + 4 * q + r;      // C/D layout: row = quad*4+reg
        int col = no + 16 * j + lr;             //             col = lane&15
        C[(long)row * N + col] = f2bf(acc[i][j][r] + pbv[j]);
      }
}

// Logits GEMM with fused exp-sum + target-logit capture (no max subtraction:
// logits are O(1), exp never overflows fp32).
__global__ __launch_bounds__(256) void gemm_logits(const short* __restrict__ A,
                                                   const short* __restrict__ BT,
                                                   const float* __restrict__ pb,
                                                   const int* __restrict__ ys,
                                                   float* __restrict__ sumexp,
                                                   float* __restrict__ logit_y,
                                                   int M, int N, int K) {
  int ntiles = N >> 7;
  int tM = (blockIdx.x / ntiles) << 7;
  int tN = (blockIdx.x % ntiles) << 7;
  int w = threadIdx.x >> 6, lane = threadIdx.x & 63;
  int mo = tM + ((w & 1) << 6), no = tN + ((w >> 1) << 6);
  int lr = lane & 15, lk8 = (lane >> 4) << 3, q = lane >> 4;
  f32x4 acc[4][4] = {};
  const short* Ap = A + (long)(mo + lr) * K + lk8;
  const short* Bp = BT + (long)(no + lr) * K + lk8;
  for (int k0 = 0; k0 < K; k0 += 32) {
    short8 af[4], bfr[4];
#pragma unroll
    for (int i = 0; i < 4; ++i) af[i] = *(const short8*)(Ap + (long)16 * i * K + k0);
#pragma unroll
    for (int j = 0; j < 4; ++j) bfr[j] = *(const short8*)(Bp + (long)16 * j * K + k0);
#pragma unroll
    for (int i = 0; i < 4; ++i)
#pragma unroll
      for (int j = 0; j < 4; ++j)
        acc[i][j] = mfma16(af[i], bfr[j], acc[i][j]);
  }
  float pbv[4];
#pragma unroll
  for (int j = 0; j < 4; ++j) pbv[j] = pb[no + 16 * j + lr];
#pragma unroll
  for (int i = 0; i < 4; ++i) {
#pragma unroll
    for (int r = 0; r < 4; ++r) {
      int row = mo + 16 * i + 4 * q + r;
      int ysr = ys[row];
      float s = 0.f;
#pragma unroll
      for (int j = 0; j < 4; ++j) {
        float v = acc[i][j][r] + pbv[j];
        s += __expf(v);
        int col = no + 16 * j + lr;
        if (col == ysr) logit_y[row] = v;   // exactly one writer grid-wide
      }
      // reduce over the 16 lanes holding this row
      s += __shfl_xor(s, 1); s += __shfl_xor(s, 2);
      s += __shfl_xor(s, 4); s += __shfl_xor(s, 8);
      if (lr == 0) atomicAdd(&sumexp[row], s);
    }
  }
}

// ---------------------------------------------------------------------------
// Persistent recurrent scan. 64 WGs x 256 threads (co-resident on 256 CUs).
// WG g owns h-columns [16g, 16g+16); c lives in a register per thread.
// Monotonic-counter grid barrier: release-add, relaxed poll, acquire fence.
#define NWG_ 64
__device__ __forceinline__ void gbar(int* cnt, int target) {
  __syncthreads();
  if (threadIdx.x == 0) {
    __hip_atomic_fetch_add(cnt, 1, __ATOMIC_RELEASE, __HIP_MEMORY_SCOPE_AGENT);
    while (__hip_atomic_load(cnt, __ATOMIC_RELAXED, __HIP_MEMORY_SCOPE_AGENT) < target)
      __builtin_amdgcn_s_sleep(2);
  }
  __syncthreads();
  __builtin_amdgcn_fence(__ATOMIC_ACQUIRE, "agent");
}

__global__ __launch_bounds__(256) void scan_kernel(const short* __restrict__ zxb,
                                                   const short* __restrict__ mxb,
                                                   const short* __restrict__ wmhT,
                                                   const short* __restrict__ whT,
                                                   short* __restrict__ hs,
                                                   short* __restrict__ h_prev,
                                                   short* __restrict__ m_buf,
                                                   int* __restrict__ bar) {
  const int g = blockIdx.x;
  const int tid = threadIdx.x;
  const int w = tid >> 6, lane = tid & 63;
  const int lr = lane & 15, lk8 = (lane >> 4) << 3, q = lane >> 4;
  const int colg = g << 4;
  const int b = tid >> 4, cl = tid & 15;
  __shared__ float red[4][16][16];

  // zero h_prev (16 x 1024 bf16 across 64*256 threads) before first step
  h_prev[(g << 8) + tid] = 0;
  int bt = 0;
  gbar(bar, (++bt) * NWG_);

  float c = 0.f;
  const short* hp_l  = h_prev + lr * H_ + lk8;                       // A: h (m=batch=lr)
  const short* wmh_l = wmhT + (long)(colg + lr) * H_ + lk8;          // B: wmh cols colg..+15
  const short* mb_l  = m_buf + lr * H_ + lk8;                        // A: m
  const short* wh_l  = whT + (long)(w * H_ + colg + lr) * H_ + lk8;  // B: gate w, cols colg..+15

  for (int t = 0; t < T_; ++t) {
    // ---- phase 1: m = mx_t * (h @ wmh_n); wave w covers k in [256w, 256w+256)
    f32x4 a1 = {};
#pragma unroll
    for (int kk = 0; kk < 8; ++kk) {
      int k = (w << 8) + (kk << 5);
      a1 = mfma16(*(const short8*)(hp_l + k), *(const short8*)(wmh_l + k), a1);
    }
#pragma unroll
    for (int r = 0; r < 4; ++r) red[w][q * 4 + r][lr] = a1[r];
    __syncthreads();
    {
      float hw = red[0][b][cl] + red[1][b][cl] + red[2][b][cl] + red[3][b][cl];
      float mval = bf2f(mxb[(long)(b * T_ + t) * H_ + colg + cl]) * hw;
      m_buf[b * H_ + colg + cl] = f2bf(mval);
    }
    gbar(bar, (++bt) * NWG_);

    // ---- phase 2: z-gate tile (wave w = gate i/f/o/u), K = 1024 over m
    f32x4 a2 = {};
#pragma unroll
    for (int kk = 0; kk < 32; ++kk) {
      int k = kk << 5;
      a2 = mfma16(*(const short8*)(mb_l + k), *(const short8*)(wh_l + k), a2);
    }
#pragma unroll
    for (int r = 0; r < 4; ++r) red[w][q * 4 + r][lr] = a2[r];
    __syncthreads();
    {
      long rrow = (long)(b * T_ + t);
      const short* zrow = zxb + rrow * H4_ + colg + cl;
      float zi = red[0][b][cl] + bf2f(zrow[0 * H_]);
      float zf = red[1][b][cl] + bf2f(zrow[1 * H_]);
      float zo = red[2][b][cl] + bf2f(zrow[2 * H_]);
      float zu = red[3][b][cl] + bf2f(zrow[3 * H_]);
      float ig = sigm(zi), fg = sigm(zf), og = sigm(zo), ug = tanh_f(zu);
      c = fg * c + ig * ug;
      float h = og * tanh_f(c);
      short hb = f2bf(h);
      h_prev[b * H_ + colg + cl] = hb;
      hs[rrow * H_ + colg + cl] = hb;
    }
    gbar(bar, (++bt) * NWG_);
  }
}

// ---------------------------------------------------------------------------
__global__ __launch_bounds__(256) void reduce_nll(const float* __restrict__ se,
                                                  const float* __restrict__ ly,
                                                  float* __restrict__ out) {
  __shared__ float buf[256];
  float s = 0.f;
  for (int r = threadIdx.x; r < BT_; r += 256)
    s += logf(se[r]) - ly[r];
  buf[threadIdx.x] = s;
  __syncthreads();
  for (int off = 128; off > 0; off >>= 1) {
    if (threadIdx.x < off) buf[threadIdx.x] += buf[threadIdx.x + off];
    __syncthreads();
  }
  if (threadIdx.x == 0) out[0] = buf[0] * (1.0f / BT_);
}

// ---------------------------------------------------------------------------
extern "C" void kernel_launch(void* const* d_in, const int* in_sizes, int n_in,
                              void* d_out, int out_size, void* d_ws, size_t ws_size,
                              hipStream_t stream) {
  const int*   xs     = (const int*)d_in[0];
  const int*   ys     = (const int*)d_in[1];
  const float* embw   = (const float*)d_in[2];
  const float* wx     = (const float*)d_in[3];
  const float* wh     = (const float*)d_in[4];
  const float* wmx    = (const float*)d_in[5];
  const float* wmh    = (const float*)d_in[6];
  const float* bias   = (const float*)d_in[7];
  const float* gx     = (const float*)d_in[8];
  const float* gh     = (const float*)d_in[9];
  const float* gmx    = (const float*)d_in[10];
  const float* gmh    = (const float*)d_in[11];
  const float* pred_w = (const float*)d_in[12];
  const float* pred_b = (const float*)d_in[13];
  float* out = (float*)d_out;

  char* base = (char*)d_ws;
  size_t off = 0;
  auto alloc = [&](size_t bytes) -> void* {
    void* p = base + off;
    off = (off + bytes + 255) & ~(size_t)255;
    return p;
  };
  short* xb     = (short*)alloc((size_t)BT_ * E_ * 2);   //  8 MB  x bf16 [8192][512]
  short* zxb    = (short*)alloc((size_t)BT_ * H4_ * 2);  // 64 MB  zx bf16 [8192][4096]
  short* mxb    = (short*)alloc((size_t)BT_ * H_ * 2);   // 16 MB  mx bf16 [8192][1024]
  short* hs     = (short*)alloc((size_t)BT_ * H_ * 2);   // 16 MB  hs bf16 [8192][1024]
  short* wxT    = (short*)alloc((size_t)H4_ * E_ * 2);   //  4 MB
  short* whT    = (short*)alloc((size_t)H4_ * H_ * 2);   //  8 MB
  short* wmxT   = (short*)alloc((size_t)H_ * E_ * 2);    //  1 MB
  short* wmhT   = (short*)alloc((size_t)H_ * H_ * 2);    //  2 MB
  short* pwb    = (short*)alloc((size_t)V_ * H_ * 2);    // 16 MB
  float* scx    = (float*)alloc(H4_ * 4);
  float* sch    = (float*)alloc(H4_ * 4);
  float* scmx   = (float*)alloc(H_ * 4);
  float* scmh   = (float*)alloc(H_ * 4);
  short* m_buf  = (short*)alloc(B_ * H_ * 2);
  short* h_prev = (short*)alloc(B_ * H_ * 2);
  float* sumexp = (float*)alloc(BT_ * 4);
  float* l_y    = (float*)alloc(BT_ * 4);
  int*   bar    = (int*)alloc(256);

  hipMemsetAsync(sumexp, 0, BT_ * 4, stream);
  hipMemsetAsync(bar, 0, 256, stream);

  // weight norm -> transposed bf16 copies
  colscale<<<H4_ / 256, 256, 0, stream>>>(wx, gx, scx, E_, H4_);
  colscale<<<H4_ / 256, 256, 0, stream>>>(wh, gh, sch, H_, H4_);
  colscale<<<H_ / 256, 256, 0, stream>>>(wmx, gmx, scmx, E_, H_);
  colscale<<<H_ / 256, 256, 0, stream>>>(wmh, gmh, scmh, H_, H_);
  transpose_cast<<<(E_ / 32) * (H4_ / 32), 256, 0, stream>>>(wx, scx, wxT, E_, H4_);
  transpose_cast<<<(H_ / 32) * (H4_ / 32), 256, 0, stream>>>(wh, sch, whT, H_, H4_);
  transpose_cast<<<(E_ / 32) * (H_ / 32), 256, 0, stream>>>(wmx, scmx, wmxT, E_, H_);
  transpose_cast<<<(H_ / 32) * (H_ / 32), 256, 0, stream>>>(wmh, scmh, wmhT, H_, H_);
  castbf<<<((long)V_ * H_) / 1024, 256, 0, stream>>>(pred_w, pwb, (long)V_ * H_);

  // embed + input-dependent projections
  embed_gather<<<BT_, 256, 0, stream>>>(xs, embw, xb);
  gemm_bt<<<(BT_ / 128) * (H4_ / 128), 256, 0, stream>>>(xb, wxT, bias, zxb, BT_, H4_, E_);
  gemm_bt<<<(BT_ / 128) * (H_ / 128), 256, 0, stream>>>(xb, wmxT, nullptr, mxb, BT_, H_, E_);

  // sequential mLSTM scan (persistent, custom grid barrier)
  scan_kernel<<<NWG_, 256, 0, stream>>>(zxb, mxb, wmhT, whT, hs, h_prev, m_buf, bar);

  // fused logits + exp-sum + target logit, then mean NLL
  gemm_logits<<<(BT_ / 128) * (V_ / 128), 256, 0, stream>>>(hs, pwb, pred_b, ys,
                                                            sumexp, l_y, BT_, V_, H_);
  reduce_nll<<<1, 256, 0, stream>>>(sumexp, l_y, out);
}

// Round 2
// 9362.949 us; speedup vs baseline: 1.1022x; 1.1022x over previous
//
#include <hip/hip_runtime.h>
#include <hip/hip_bf16.h>
#include <stdint.h>

// Problem dims (fixed by reference)
#define B_   16
#define T_   512
#define V_   8192
#define E_   512
#define H_   1024
#define BT_  (B_ * T_)   // 8192 rows, row r = b*T + t
#define H4_  (4 * H_)    // 4096

typedef __attribute__((ext_vector_type(8))) short   short8;
typedef __attribute__((ext_vector_type(8))) __bf16  bf16x8;
typedef __attribute__((ext_vector_type(4))) float   f32x4;
typedef __attribute__((ext_vector_type(4))) short   short4v;

__device__ __forceinline__ float bf2f(short s) {
  union { unsigned u; float f; } x;
  x.u = ((unsigned)(unsigned short)s) << 16;
  return x.f;
}
__device__ __forceinline__ short f2bf(float f) {
  union { float f; unsigned u; } x; x.f = f;
  unsigned u = x.u;
  u = (u + 0x7fffu + ((u >> 16) & 1u)) >> 16;   // RNE
  return (short)u;
}
__device__ __forceinline__ f32x4 mfma16(short8 a, short8 b, f32x4 c) {
  return __builtin_amdgcn_mfma_f32_16x16x32_bf16(
      __builtin_bit_cast(bf16x8, a), __builtin_bit_cast(bf16x8, b), c, 0, 0, 0);
}
__device__ __forceinline__ float sigm(float x) { return 1.f / (1.f + __expf(-x)); }
__device__ __forceinline__ float tanh_f(float x) { return 1.f - 2.f / (__expf(2.f * x) + 1.f); }

// agent-scope (cross-XCD coherent, cache-bypassing) 8-byte exchange ops
__device__ __forceinline__ short8 ld_frag_agent(const unsigned long long* p) {
  unsigned long long lo = __hip_atomic_load(p,     __ATOMIC_RELAXED, __HIP_MEMORY_SCOPE_AGENT);
  unsigned long long hi = __hip_atomic_load(p + 1, __ATOMIC_RELAXED, __HIP_MEMORY_SCOPE_AGENT);
  union { unsigned long long u[2]; short8 s; } c;
  c.u[0] = lo; c.u[1] = hi;
  return c.s;
}

// ---------------------------------------------------------------------------
// 1) column L2-norm scales: sc[j] = g[j] / max(||W[:,j]||, 1e-12)
__global__ __launch_bounds__(256) void colscale(const float* __restrict__ W,
                                                const float* __restrict__ g,
                                                float* __restrict__ sc, int Kr, int N) {
  int j = blockIdx.x * 256 + threadIdx.x;
  if (j >= N) return;
  float ss = 0.f;
  for (int i = 0; i < Kr; ++i) { float v = W[(long)i * N + j]; ss = fmaf(v, v, ss); }
  sc[j] = g[j] / fmaxf(sqrtf(ss), 1e-12f);
}

// 2) WT[j][i] = bf16(W[i][j] * sc[j]) — LDS 32x32 tile transpose
__global__ __launch_bounds__(256) void transpose_cast(const float* __restrict__ W,
                                                      const float* __restrict__ sc,
                                                      short* __restrict__ WT, int Kr, int N) {
  __shared__ float tile[32][33];
  int nbi = Kr >> 5;
  int bi = blockIdx.x % nbi, bj = blockIdx.x / nbi;
  int i0 = bi << 5, j0 = bj << 5;
  int tx = threadIdx.x & 31, ty = threadIdx.x >> 5;   // 32 x 8
  for (int yy = ty; yy < 32; yy += 8)
    tile[yy][tx] = W[(long)(i0 + yy) * N + j0 + tx];
  __syncthreads();
  for (int yy = ty; yy < 32; yy += 8) {
    int j = j0 + yy;
    WT[(long)j * Kr + i0 + tx] = f2bf(tile[tx][yy] * sc[j]);
  }
}

// 3) plain f32 -> bf16 cast
__global__ __launch_bounds__(256) void castbf(const float* __restrict__ src,
                                              short* __restrict__ dst, long n) {
  long i = ((long)blockIdx.x * 256 + threadIdx.x) * 4;
  if (i + 3 < n) {
    float4 v = *(const float4*)(src + i);
    short4v o = { f2bf(v.x), f2bf(v.y), f2bf(v.z), f2bf(v.w) };
    *(short4v*)(dst + i) = o;
  }
}

// 4) embedding gather with padding_idx=0 -> zeros
__global__ __launch_bounds__(256) void embed_gather(const int* __restrict__ xs,
                                                    const float* __restrict__ ew,
                                                    short* __restrict__ x) {
  int r = blockIdx.x;
  int idx = xs[r];
  const float* src = ew + (long)idx * E_;
  for (int e = threadIdx.x; e < E_; e += 256) {
    float v = (idx == 0) ? 0.f : src[e];
    x[(long)r * E_ + e] = f2bf(v);
  }
}

// ---------------------------------------------------------------------------
// Generic 128x128-tile bf16 MFMA GEMM: C[M][N](bf16) = A[M][K] @ BT[N][K]^T (+bias)
__global__ __launch_bounds__(256) void gemm_bt(const short* __restrict__ A,
                                               const short* __restrict__ BT,
                                               const float* __restrict__ bias,
                                               short* __restrict__ C,
                                               int M, int N, int K) {
  int ntiles = N >> 7;
  int tM = (blockIdx.x / ntiles) << 7;
  int tN = (blockIdx.x % ntiles) << 7;
  int w = threadIdx.x >> 6, lane = threadIdx.x & 63;
  int mo = tM + ((w & 1) << 6), no = tN + ((w >> 1) << 6);
  int lr = lane & 15, lk8 = (lane >> 4) << 3, q = lane >> 4;
  f32x4 acc[4][4] = {};
  const short* Ap = A + (long)(mo + lr) * K + lk8;
  const short* Bp = BT + (long)(no + lr) * K + lk8;
  for (int k0 = 0; k0 < K; k0 += 32) {
    short8 af[4], bfr[4];
#pragma unroll
    for (int i = 0; i < 4; ++i) af[i] = *(const short8*)(Ap + (long)16 * i * K + k0);
#pragma unroll
    for (int j = 0; j < 4; ++j) bfr[j] = *(const short8*)(Bp + (long)16 * j * K + k0);
#pragma unroll
    for (int i = 0; i < 4; ++i)
#pragma unroll
      for (int j = 0; j < 4; ++j)
        acc[i][j] = mfma16(af[i], bfr[j], acc[i][j]);
  }
  float pbv[4];
#pragma unroll
  for (int j = 0; j < 4; ++j) pbv[j] = bias ? bias[no + 16 * j + lr] : 0.f;
#pragma unroll
  for (int i = 0; i < 4; ++i)
#pragma unroll
    for (int j = 0; j < 4; ++j)
#pragma unroll
      for (int r = 0; r < 4; ++r) {
        int row = mo + 16 * i + 4 * q + r;      // C/D layout: row = quad*4+reg
        int col = no + 16 * j + lr;             //             col = lane&15
        C[(long)row * N + col] = f2bf(acc[i][j][r] + pbv[j]);
      }
}

// Logits GEMM with fused exp-sum + target-logit capture
__global__ __launch_bounds__(256) void gemm_logits(const short* __restrict__ A,
                                                   const short* __restrict__ BT,
                                                   const float* __restrict__ pb,
                                                   const int* __restrict__ ys,
                                                   float* __restrict__ sumexp,
                                                   float* __restrict__ logit_y,
                                                   int M, int N, int K) {
  int ntiles = N >> 7;
  int tM = (blockIdx.x / ntiles) << 7;
  int tN = (blockIdx.x % ntiles) << 7;
  int w = threadIdx.x >> 6, lane = threadIdx.x & 63;
  int mo = tM + ((w & 1) << 6), no = tN + ((w >> 1) << 6);
  int lr = lane & 15, lk8 = (lane >> 4) << 3, q = lane >> 4;
  f32x4 acc[4][4] = {};
  const short* Ap = A + (long)(mo + lr) * K + lk8;
  const short* Bp = BT + (long)(no + lr) * K + lk8;
  for (int k0 = 0; k0 < K; k0 += 32) {
    short8 af[4], bfr[4];
#pragma unroll
    for (int i = 0; i < 4; ++i) af[i] = *(const short8*)(Ap + (long)16 * i * K + k0);
#pragma unroll
    for (int j = 0; j < 4; ++j) bfr[j] = *(const short8*)(Bp + (long)16 * j * K + k0);
#pragma unroll
    for (int i = 0; i < 4; ++i)
#pragma unroll
      for (int j = 0; j < 4; ++j)
        acc[i][j] = mfma16(af[i], bfr[j], acc[i][j]);
  }
  float pbv[4];
#pragma unroll
  for (int j = 0; j < 4; ++j) pbv[j] = pb[no + 16 * j + lr];
#pragma unroll
  for (int i = 0; i < 4; ++i) {
#pragma unroll
    for (int r = 0; r < 4; ++r) {
      int row = mo + 16 * i + 4 * q + r;
      int ysr = ys[row];
      float s = 0.f;
#pragma unroll
      for (int j = 0; j < 4; ++j) {
        float v = acc[i][j][r] + pbv[j];
        s += __expf(v);
        int col = no + 16 * j + lr;
        if (col == ysr) logit_y[row] = v;
      }
      s += __shfl_xor(s, 1); s += __shfl_xor(s, 2);
      s += __shfl_xor(s, 4); s += __shfl_xor(s, 8);
      if (lr == 0) atomicAdd(&sumexp[row], s);
    }
  }
}

// ---------------------------------------------------------------------------
// Persistent recurrent scan. 64 WGs x 256 threads, weights register-resident.
// Exchange via RELAXED agent-scope atomics (sc0/sc1: bypass non-coherent L1/L2,
// no wbL2/inv cache maintenance). Contention-free flag barrier.
#define NWG_ 64

__device__ __forceinline__ void gbar2(unsigned* flags, unsigned* go,
                                      unsigned tick, int g) {
  __builtin_amdgcn_s_waitcnt(0);          // drain this wave's exchange stores
  __syncthreads();                        // all waves' stores drained
  __atomic_signal_fence(__ATOMIC_SEQ_CST);
  if (threadIdx.x == 0)
    __hip_atomic_store(&flags[g * 32], tick, __ATOMIC_RELAXED, __HIP_MEMORY_SCOPE_AGENT);
  if (g == 0 && threadIdx.x < NWG_) {
    while (__hip_atomic_load(&flags[threadIdx.x * 32], __ATOMIC_RELAXED,
                             __HIP_MEMORY_SCOPE_AGENT) < tick) {}
    // wave reconverges only when all 64 flags reached tick
    if (threadIdx.x == 0)
      __hip_atomic_store(go, tick, __ATOMIC_RELAXED, __HIP_MEMORY_SCOPE_AGENT);
  }
  if (threadIdx.x == 0)
    while (__hip_atomic_load(go, __ATOMIC_RELAXED, __HIP_MEMORY_SCOPE_AGENT) < tick) {}
  __atomic_signal_fence(__ATOMIC_SEQ_CST);
  __syncthreads();
}

__global__ __launch_bounds__(256, 1) void scan_kernel(
    const short* __restrict__ zxb, const short* __restrict__ mxb,
    const short* __restrict__ wmhT, const short* __restrict__ whT,
    short* __restrict__ hs,
    unsigned long long* __restrict__ h_prev,    // [16][1024] bf16 as ull[4096], memset 0
    unsigned long long* __restrict__ m_buf,     // [16][1024] bf16 as ull[4096]
    unsigned* __restrict__ flags, unsigned* __restrict__ go) {
  const int g = blockIdx.x;
  const int tid = threadIdx.x;
  const int w = tid >> 6, lane = tid & 63;
  const int lr = lane & 15, q = lane >> 4, lk8 = q << 3;
  const int colg = g << 4;
  const int b = tid >> 4, cl = tid & 15;
  __shared__ float red[4][16][16];
  __shared__ __align__(16) short htile[16][16];
  __shared__ __align__(16) short mtile[16][16];

  // ---- preload weights into registers (read once from HBM/L2) ----
  short8 wmh_f[8];      // phase1 B: col = colg+lr, k = w*256 + kk*32 + q*8
#pragma unroll
  for (int kk = 0; kk < 8; ++kk)
    wmh_f[kk] = *(const short8*)(wmhT + (long)(colg + lr) * H_ + (w << 8) + (kk << 5) + lk8);
  short8 wh_f[32];      // phase2 B: gate w, col = colg+lr, k = kk*32 + q*8
#pragma unroll
  for (int kk = 0; kk < 32; ++kk)
    wh_f[kk] = *(const short8*)(whT + (long)(w * H_ + colg + lr) * H_ + (kk << 5) + lk8);

  float c = 0.f;
  unsigned tick = 0;

  for (int t = 0; t < T_; ++t) {
    // prefetch this step's zx/mx values (independent of barriers; hides HBM)
    long rrow = (long)(b * T_ + t);
    short mx_p = mxb[rrow * H_ + colg + cl];
    const short* zrow = zxb + rrow * H4_ + colg + cl;
    short z0p = zrow[0 * H_], z1p = zrow[1 * H_], z2p = zrow[2 * H_], z3p = zrow[3 * H_];

    // ---- phase 1: m = mx_t * (h @ wmh_n); wave w covers k in [256w, 256w+256)
    f32x4 a1 = {};
#pragma unroll
    for (int kk = 0; kk < 8; ++kk) {
      // h_prev ull index: (lr*1024 + w*256 + kk*32 + q*8) / 4
      short8 af = ld_frag_agent(h_prev + lr * 256 + (w << 6) + (kk << 3) + (q << 1));
      a1 = mfma16(af, wmh_f[kk], a1);
    }
#pragma unroll
    for (int r = 0; r < 4; ++r) red[w][q * 4 + r][lr] = a1[r];
    __syncthreads();
    {
      float hw = red[0][b][cl] + red[1][b][cl] + red[2][b][cl] + red[3][b][cl];
      mtile[b][cl] = f2bf(bf2f(mx_p) * hw);
    }
    __syncthreads();
    if (tid < 64) {
      int b2 = tid >> 2, ch = tid & 3;
      unsigned long long v = *(const unsigned long long*)&mtile[b2][ch << 2];
      __hip_atomic_store(&m_buf[b2 * 256 + (colg >> 2) + ch], v,
                         __ATOMIC_RELAXED, __HIP_MEMORY_SCOPE_AGENT);
    }
    gbar2(flags, go, ++tick, g);

    // ---- phase 2: z-gate tile (wave w = gate w), K = 1024 over m
    f32x4 a2 = {};
#pragma unroll
    for (int kk = 0; kk < 32; ++kk) {
      short8 af = ld_frag_agent(m_buf + lr * 256 + (kk << 3) + (q << 1));
      a2 = mfma16(af, wh_f[kk], a2);
    }
#pragma unroll
    for (int r = 0; r < 4; ++r) red[w][q * 4 + r][lr] = a2[r];
    __syncthreads();
    {
      float zi = red[0][b][cl] + bf2f(z0p);
      float zf = red[1][b][cl] + bf2f(z1p);
      float zo = red[2][b][cl] + bf2f(z2p);
      float zu = red[3][b][cl] + bf2f(z3p);
      float ig = sigm(zi), fg = sigm(zf), og = sigm(zo), ug = tanh_f(zu);
      c = fg * c + ig * ug;
      float h = og * tanh_f(c);
      short hb = f2bf(h);
      htile[b][cl] = hb;
      hs[rrow * H_ + colg + cl] = hb;    // plain store; consumed after kernel end
    }
    __syncthreads();
    if (tid < 64) {
      int b2 = tid >> 2, ch = tid & 3;
      unsigned long long v = *(const unsigned long long*)&htile[b2][ch << 2];
      __hip_atomic_store(&h_prev[b2 * 256 + (colg >> 2) + ch], v,
                         __ATOMIC_RELAXED, __HIP_MEMORY_SCOPE_AGENT);
    }
    gbar2(flags, go, ++tick, g);
  }
}

// ---------------------------------------------------------------------------
__global__ __launch_bounds__(256) void reduce_nll(const float* __restrict__ se,
                                                  const float* __restrict__ ly,
                                                  float* __restrict__ out) {
  __shared__ float buf[256];
  float s = 0.f;
  for (int r = threadIdx.x; r < BT_; r += 256)
    s += logf(se[r]) - ly[r];
  buf[threadIdx.x] = s;
  __syncthreads();
  for (int off = 128; off > 0; off >>= 1) {
    if (threadIdx.x < off) buf[threadIdx.x] += buf[threadIdx.x + off];
    __syncthreads();
  }
  if (threadIdx.x == 0) out[0] = buf[0] * (1.0f / BT_);
}

// ---------------------------------------------------------------------------
extern "C" void kernel_launch(void* const* d_in, const int* in_sizes, int n_in,
                              void* d_out, int out_size, void* d_ws, size_t ws_size,
                              hipStream_t stream) {
  const int*   xs     = (const int*)d_in[0];
  const int*   ys     = (const int*)d_in[1];
  const float* embw   = (const float*)d_in[2];
  const float* wx     = (const float*)d_in[3];
  const float* wh     = (const float*)d_in[4];
  const float* wmx    = (const float*)d_in[5];
  const float* wmh    = (const float*)d_in[6];
  const float* bias   = (const float*)d_in[7];
  const float* gx     = (const float*)d_in[8];
  const float* gh     = (const float*)d_in[9];
  const float* gmx    = (const float*)d_in[10];
  const float* gmh    = (const float*)d_in[11];
  const float* pred_w = (const float*)d_in[12];
  const float* pred_b = (const float*)d_in[13];
  float* out = (float*)d_out;

  char* base = (char*)d_ws;
  size_t off = 0;
  auto alloc = [&](size_t bytes) -> void* {
    void* p = base + off;
    off = (off + bytes + 255) & ~(size_t)255;
    return p;
  };
  short* xb     = (short*)alloc((size_t)BT_ * E_ * 2);   //  8 MB
  short* zxb    = (short*)alloc((size_t)BT_ * H4_ * 2);  // 64 MB
  short* mxb    = (short*)alloc((size_t)BT_ * H_ * 2);   // 16 MB
  short* hs     = (short*)alloc((size_t)BT_ * H_ * 2);   // 16 MB
  short* wxT    = (short*)alloc((size_t)H4_ * E_ * 2);   //  4 MB
  short* whT    = (short*)alloc((size_t)H4_ * H_ * 2);   //  8 MB
  short* wmxT   = (short*)alloc((size_t)H_ * E_ * 2);    //  1 MB
  short* wmhT   = (short*)alloc((size_t)H_ * H_ * 2);    //  2 MB
  short* pwb    = (short*)alloc((size_t)V_ * H_ * 2);    // 16 MB
  float* scx    = (float*)alloc(H4_ * 4);
  float* sch    = (float*)alloc(H4_ * 4);
  float* scmx   = (float*)alloc(H_ * 4);
  float* scmh   = (float*)alloc(H_ * 4);
  float* l_y    = (float*)alloc(BT_ * 4);
  short* m_bufs = (short*)alloc(B_ * H_ * 2);            // m_buf (no init needed)
  // ---- zero zone (one memset covers all of these) ----
  size_t z0 = off;
  float*    sumexp = (float*)alloc(BT_ * 4);                       // 32 KB
  unsigned* flags  = (unsigned*)alloc(NWG_ * 32 * 4);              //  8 KB
  unsigned* go     = (unsigned*)alloc(256);
  unsigned long long* h_prev = (unsigned long long*)alloc(B_ * H_ * 2);  // 32 KB
  size_t zlen = off - z0;

  hipMemsetAsync(base + z0, 0, zlen, stream);

  // weight norm -> transposed bf16 copies
  colscale<<<H4_ / 256, 256, 0, stream>>>(wx, gx, scx, E_, H4_);
  colscale<<<H4_ / 256, 256, 0, stream>>>(wh, gh, sch, H_, H4_);
  colscale<<<H_ / 256, 256, 0, stream>>>(wmx, gmx, scmx, E_, H_);
  colscale<<<H_ / 256, 256, 0, stream>>>(wmh, gmh, scmh, H_, H_);
  transpose_cast<<<(E_ / 32) * (H4_ / 32), 256, 0, stream>>>(wx, scx, wxT, E_, H4_);
  transpose_cast<<<(H_ / 32) * (H4_ / 32), 256, 0, stream>>>(wh, sch, whT, H_, H4_);
  transpose_cast<<<(E_ / 32) * (H_ / 32), 256, 0, stream>>>(wmx, scmx, wmxT, E_, H_);
  transpose_cast<<<(H_ / 32) * (H_ / 32), 256, 0, stream>>>(wmh, scmh, wmhT, H_, H_);
  castbf<<<((long)V_ * H_) / 1024, 256, 0, stream>>>(pred_w, pwb, (long)V_ * H_);

  // embed + input-dependent projections
  embed_gather<<<BT_, 256, 0, stream>>>(xs, embw, xb);
  gemm_bt<<<(BT_ / 128) * (H4_ / 128), 256, 0, stream>>>(xb, wxT, bias, zxb, BT_, H4_, E_);
  gemm_bt<<<(BT_ / 128) * (H_ / 128), 256, 0, stream>>>(xb, wmxT, nullptr, mxb, BT_, H_, E_);

  // sequential mLSTM scan (persistent, register-resident weights, flag barrier)
  scan_kernel<<<NWG_, 256, 0, stream>>>(zxb, mxb, wmhT, whT, hs,
                                        h_prev, (unsigned long long*)m_bufs, flags, go);

  // fused logits + exp-sum + target logit, then mean NLL
  gemm_logits<<<(BT_ / 128) * (V_ / 128), 256, 0, stream>>>(hs, pwb, pred_b, ys,
                                                            sumexp, l_y, BT_, V_, H_);
  reduce_nll<<<1, 256, 0, stream>>>(sumexp, l_y, out);
}

// Round 5
// 5773.510 us; speedup vs baseline: 1.7874x; 1.6217x over previous
//
#include <hip/hip_runtime.h>
#include <hip/hip_bf16.h>
#include <stdint.h>

// Problem dims (fixed by reference)
#define B_   16
#define T_   512
#define V_   8192
#define E_   512
#define H_   1024
#define BT_  (B_ * T_)   // 8192 rows, row r = b*T + t
#define H4_  (4 * H_)    // 4096

typedef __attribute__((ext_vector_type(8))) short   short8;
typedef __attribute__((ext_vector_type(8))) __bf16  bf16x8;
typedef __attribute__((ext_vector_type(4))) float   f32x4;
typedef __attribute__((ext_vector_type(4))) short   short4v;
typedef unsigned long long ull;

__device__ __forceinline__ float bf2f(short s) {
  union { unsigned u; float f; } x;
  x.u = ((unsigned)(unsigned short)s) << 16;
  return x.f;
}
__device__ __forceinline__ short f2bf(float f) {
  union { float f; unsigned u; } x; x.f = f;
  unsigned u = x.u;
  u = (u + 0x7fffu + ((u >> 16) & 1u)) >> 16;   // RNE
  return (short)u;
}
__device__ __forceinline__ f32x4 mfma16(short8 a, short8 b, f32x4 c) {
  return __builtin_amdgcn_mfma_f32_16x16x32_bf16(
      __builtin_bit_cast(bf16x8, a), __builtin_bit_cast(bf16x8, b), c, 0, 0, 0);
}
__device__ __forceinline__ float sigm(float x) { return 1.f / (1.f + __expf(-x)); }
__device__ __forceinline__ float tanh_f(float x) { return 1.f - 2.f / (__expf(2.f * x) + 1.f); }

__device__ __forceinline__ short8 mk8(ull lo, ull hi) {
  union { ull u[2]; short8 s; } c;
  c.u[0] = lo; c.u[1] = hi;
  return c.s;
}

// ---------------------------------------------------------------------------
// 1) column L2-norm scales
__global__ __launch_bounds__(256) void colscale(const float* __restrict__ W,
                                                const float* __restrict__ g,
                                                float* __restrict__ sc, int Kr, int N) {
  int j = blockIdx.x * 256 + threadIdx.x;
  if (j >= N) return;
  float ss = 0.f;
  for (int i = 0; i < Kr; ++i) { float v = W[(long)i * N + j]; ss = fmaf(v, v, ss); }
  sc[j] = g[j] / fmaxf(sqrtf(ss), 1e-12f);
}

// 2) WT[j][i] = bf16(W[i][j] * sc[j]) — LDS 32x32 tile transpose
__global__ __launch_bounds__(256) void transpose_cast(const float* __restrict__ W,
                                                      const float* __restrict__ sc,
                                                      short* __restrict__ WT, int Kr, int N) {
  __shared__ float tile[32][33];
  int nbi = Kr >> 5;
  int bi = blockIdx.x % nbi, bj = blockIdx.x / nbi;
  int i0 = bi << 5, j0 = bj << 5;
  int tx = threadIdx.x & 31, ty = threadIdx.x >> 5;   // 32 x 8
  for (int yy = ty; yy < 32; yy += 8)
    tile[yy][tx] = W[(long)(i0 + yy) * N + j0 + tx];
  __syncthreads();
  for (int yy = ty; yy < 32; yy += 8) {
    int j = j0 + yy;
    WT[(long)j * Kr + i0 + tx] = f2bf(tile[tx][yy] * sc[j]);
  }
}

// 3) plain f32 -> bf16 cast
__global__ __launch_bounds__(256) void castbf(const float* __restrict__ src,
                                              short* __restrict__ dst, long n) {
  long i = ((long)blockIdx.x * 256 + threadIdx.x) * 4;
  if (i + 3 < n) {
    float4 v = *(const float4*)(src + i);
    short4v o = { f2bf(v.x), f2bf(v.y), f2bf(v.z), f2bf(v.w) };
    *(short4v*)(dst + i) = o;
  }
}

// 4) embedding gather with padding_idx=0 -> zeros
__global__ __launch_bounds__(256) void embed_gather(const int* __restrict__ xs,
                                                    const float* __restrict__ ew,
                                                    short* __restrict__ x) {
  int r = blockIdx.x;
  int idx = xs[r];
  const float* src = ew + (long)idx * E_;
  for (int e = threadIdx.x; e < E_; e += 256) {
    float v = (idx == 0) ? 0.f : src[e];
    x[(long)r * E_ + e] = f2bf(v);
  }
}

// ---------------------------------------------------------------------------
// Generic 128x128-tile bf16 MFMA GEMM: C[M][N](bf16) = A[M][K] @ BT[N][K]^T (+bias)
__global__ __launch_bounds__(256) void gemm_bt(const short* __restrict__ A,
                                               const short* __restrict__ BT,
                                               const float* __restrict__ bias,
                                               short* __restrict__ C,
                                               int M, int N, int K) {
  int ntiles = N >> 7;
  int tM = (blockIdx.x / ntiles) << 7;
  int tN = (blockIdx.x % ntiles) << 7;
  int w = threadIdx.x >> 6, lane = threadIdx.x & 63;
  int mo = tM + ((w & 1) << 6), no = tN + ((w >> 1) << 6);
  int lr = lane & 15, lk8 = (lane >> 4) << 3, q = lane >> 4;
  f32x4 acc[4][4] = {};
  const short* Ap = A + (long)(mo + lr) * K + lk8;
  const short* Bp = BT + (long)(no + lr) * K + lk8;
  for (int k0 = 0; k0 < K; k0 += 32) {
    short8 af[4], bfr[4];
#pragma unroll
    for (int i = 0; i < 4; ++i) af[i] = *(const short8*)(Ap + (long)16 * i * K + k0);
#pragma unroll
    for (int j = 0; j < 4; ++j) bfr[j] = *(const short8*)(Bp + (long)16 * j * K + k0);
#pragma unroll
    for (int i = 0; i < 4; ++i)
#pragma unroll
      for (int j = 0; j < 4; ++j)
        acc[i][j] = mfma16(af[i], bfr[j], acc[i][j]);
  }
  float pbv[4];
#pragma unroll
  for (int j = 0; j < 4; ++j) pbv[j] = bias ? bias[no + 16 * j + lr] : 0.f;
#pragma unroll
  for (int i = 0; i < 4; ++i)
#pragma unroll
    for (int j = 0; j < 4; ++j)
#pragma unroll
      for (int r = 0; r < 4; ++r) {
        int row = mo + 16 * i + 4 * q + r;      // C/D layout: row = quad*4+reg
        int col = no + 16 * j + lr;             //             col = lane&15
        C[(long)row * N + col] = f2bf(acc[i][j][r] + pbv[j]);
      }
}

// Logits GEMM with fused exp-sum + target-logit capture
__global__ __launch_bounds__(256) void gemm_logits(const short* __restrict__ A,
                                                   const short* __restrict__ BT,
                                                   const float* __restrict__ pb,
                                                   const int* __restrict__ ys,
                                                   float* __restrict__ sumexp,
                                                   float* __restrict__ logit_y,
                                                   int M, int N, int K) {
  int ntiles = N >> 7;
  int tM = (blockIdx.x / ntiles) << 7;
  int tN = (blockIdx.x % ntiles) << 7;
  int w = threadIdx.x >> 6, lane = threadIdx.x & 63;
  int mo = tM + ((w & 1) << 6), no = tN + ((w >> 1) << 6);
  int lr = lane & 15, lk8 = (lane >> 4) << 3, q = lane >> 4;
  f32x4 acc[4][4] = {};
  const short* Ap = A + (long)(mo + lr) * K + lk8;
  const short* Bp = BT + (long)(no + lr) * K + lk8;
  for (int k0 = 0; k0 < K; k0 += 32) {
    short8 af[4], bfr[4];
#pragma unroll
    for (int i = 0; i < 4; ++i) af[i] = *(const short8*)(Ap + (long)16 * i * K + k0);
#pragma unroll
    for (int j = 0; j < 4; ++j) bfr[j] = *(const short8*)(Bp + (long)16 * j * K + k0);
#pragma unroll
    for (int i = 0; i < 4; ++i)
#pragma unroll
      for (int j = 0; j < 4; ++j)
        acc[i][j] = mfma16(af[i], bfr[j], acc[i][j]);
  }
  float pbv[4];
#pragma unroll
  for (int j = 0; j < 4; ++j) pbv[j] = pb[no + 16 * j + lr];
#pragma unroll
  for (int i = 0; i < 4; ++i) {
#pragma unroll
    for (int r = 0; r < 4; ++r) {
      int row = mo + 16 * i + 4 * q + r;
      int ysr = ys[row];
      float s = 0.f;
#pragma unroll
      for (int j = 0; j < 4; ++j) {
        float v = acc[i][j][r] + pbv[j];
        s += __expf(v);
        int col = no + 16 * j + lr;
        if (col == ysr) logit_y[row] = v;
      }
      s += __shfl_xor(s, 1); s += __shfl_xor(s, 2);
      s += __shfl_xor(s, 4); s += __shfl_xor(s, 8);
      if (lr == 0) atomicAdd(&sumexp[row], s);
    }
  }
}

// ---------------------------------------------------------------------------
// Persistent recurrent scan. 64 WGs x 256 threads (co-resident on 256 CUs).
// WG g owns h-columns [16g,16g+16). Exchange via RELAXED agent-scope atomics,
// BATCHED (all loads issued before MFMAs -> one LIC round-trip, not 32).
// Weights preloaded via workgroup-scope atomic loads (non-rematerializable ->
// forced register-resident). Flattened per-WG flag barrier (no aggregator).
#define NWG_ 64

__global__ __launch_bounds__(256, 1) void scan_kernel(
    const short* __restrict__ zxb, const short* __restrict__ mxb,
    const short* __restrict__ wmhT, const short* __restrict__ whT,
    short* __restrict__ hs,
    ull* __restrict__ h_prev,       // [16][1024] bf16 as ull[4096], memset 0
    ull* __restrict__ m_buf,        // [16][1024] bf16 as ull[4096]
    unsigned* __restrict__ flags_m, // [64] epoch flags, stride 32 uints
    unsigned* __restrict__ flags_h) {
  const int g = blockIdx.x;
  const int tid = threadIdx.x;
  const int w = tid >> 6, lane = tid & 63;
  const int lr = lane & 15, q = lane >> 4;
  const int colg = g << 4;
  const int b = tid >> 4, cl = tid & 15;

  __shared__ float red1[4][16][16];          //  4 KB
  __shared__ float red2[4][4][16][16];       // 16 KB
  __shared__ __align__(8) short mtile[16][16];
  __shared__ __align__(8) short htile[16][16];

  // ---- preload weights into registers (atomic loads: cannot rematerialize) ----
  // wmh_f[kk]: phase1 B-frag, col colg+lr, k = w*256 + kk*32 + q*8
  short8 wmh_f[8];
#pragma unroll
  for (int kk = 0; kk < 8; ++kk) {
    const ull* p = (const ull*)(wmhT + (long)(colg + lr) * H_ + (w << 8) + (kk << 5) + (q << 3));
    ull lo = __hip_atomic_load(p, __ATOMIC_RELAXED, __HIP_MEMORY_SCOPE_WORKGROUP);
    ull hi = __hip_atomic_load(p + 1, __ATOMIC_RELAXED, __HIP_MEMORY_SCOPE_WORKGROUP);
    wmh_f[kk] = mk8(lo, hi);
  }
  // wh_f[gate][kk]: phase2 B-frag, col = gate*H + colg + lr, k = w*256 + kk*32 + q*8
  short8 wh_f[4][8];
#pragma unroll
  for (int gt = 0; gt < 4; ++gt)
#pragma unroll
    for (int kk = 0; kk < 8; ++kk) {
      const ull* p = (const ull*)(whT + (long)(gt * H_ + colg + lr) * H_ + (w << 8) + (kk << 5) + (q << 3));
      ull lo = __hip_atomic_load(p, __ATOMIC_RELAXED, __HIP_MEMORY_SCOPE_WORKGROUP);
      ull hi = __hip_atomic_load(p + 1, __ATOMIC_RELAXED, __HIP_MEMORY_SCOPE_WORKGROUP);
      wh_f[gt][kk] = mk8(lo, hi);
    }

  float c = 0.f;
  // A-frag base (ull index): (lr*1024 + w*256 + q*8)/4
  const ull* hp = h_prev + lr * 256 + (w << 6) + (q << 1);
  const ull* mp = m_buf + lr * 256 + (w << 6) + (q << 1);

  for (int t = 0; t < T_; ++t) {
    // prefetch this step's zx/mx (plain cached loads; overlap the polls)
    long rrow = (long)(b * T_ + t);
    short mx_p = mxb[rrow * H_ + colg + cl];
    const short* zrow = zxb + rrow * H4_ + colg + cl;
    short z0p = zrow[0 * H_], z1p = zrow[1 * H_], z2p = zrow[2 * H_], z3p = zrow[3 * H_];

    // ---- phase 1: wait h(t), m = mx_t * (h @ wmh) ----
    if (tid < NWG_)
      while (__hip_atomic_load(&flags_h[tid << 5], __ATOMIC_RELAXED,
                               __HIP_MEMORY_SCOPE_AGENT) < (unsigned)t) {}
    __syncthreads();

    ull lh[16];
#pragma unroll
    for (int kk = 0; kk < 8; ++kk) {
      lh[2 * kk]     = __hip_atomic_load(hp + (kk << 3),     __ATOMIC_RELAXED, __HIP_MEMORY_SCOPE_AGENT);
      lh[2 * kk + 1] = __hip_atomic_load(hp + (kk << 3) + 1, __ATOMIC_RELAXED, __HIP_MEMORY_SCOPE_AGENT);
    }
    f32x4 a1 = {};
#pragma unroll
    for (int kk = 0; kk < 8; ++kk)
      a1 = mfma16(mk8(lh[2 * kk], lh[2 * kk + 1]), wmh_f[kk], a1);
#pragma unroll
    for (int r = 0; r < 4; ++r) red1[w][q * 4 + r][lr] = a1[r];
    __syncthreads();
    {
      float hw = red1[0][b][cl] + red1[1][b][cl] + red1[2][b][cl] + red1[3][b][cl];
      mtile[b][cl] = f2bf(bf2f(mx_p) * hw);
    }
    __syncthreads();
    if (tid < 64) {            // wave 0 exactly: stores + drain + flag, in-wave order
      int b2 = tid >> 2, ch = tid & 3;
      ull v = *(const ull*)&mtile[b2][ch << 2];
      __hip_atomic_store(&m_buf[b2 * 256 + (colg >> 2) + ch], v,
                         __ATOMIC_RELAXED, __HIP_MEMORY_SCOPE_AGENT);
      __builtin_amdgcn_s_waitcnt(0);   // wave-0 stores committed at LIC
      if (tid == 0)
        __hip_atomic_store(&flags_m[g << 5], (unsigned)(t + 1),
                           __ATOMIC_RELAXED, __HIP_MEMORY_SCOPE_AGENT);
    }

    // ---- phase 2: wait all m(t), z = zx + m @ wh (k-split), gates ----
    if (tid < NWG_)
      while (__hip_atomic_load(&flags_m[tid << 5], __ATOMIC_RELAXED,
                               __HIP_MEMORY_SCOPE_AGENT) < (unsigned)(t + 1)) {}
    __syncthreads();

    ull lm[16];
#pragma unroll
    for (int kk = 0; kk < 8; ++kk) {
      lm[2 * kk]     = __hip_atomic_load(mp + (kk << 3),     __ATOMIC_RELAXED, __HIP_MEMORY_SCOPE_AGENT);
      lm[2 * kk + 1] = __hip_atomic_load(mp + (kk << 3) + 1, __ATOMIC_RELAXED, __HIP_MEMORY_SCOPE_AGENT);
    }
    f32x4 a2[4] = {};
#pragma unroll
    for (int kk = 0; kk < 8; ++kk) {
      short8 mf = mk8(lm[2 * kk], lm[2 * kk + 1]);
#pragma unroll
      for (int gt = 0; gt < 4; ++gt)
        a2[gt] = mfma16(mf, wh_f[gt][kk], a2[gt]);
    }
#pragma unroll
    for (int gt = 0; gt < 4; ++gt)
#pragma unroll
      for (int r = 0; r < 4; ++r)
        red2[w][gt][q * 4 + r][lr] = a2[gt][r];
    __syncthreads();
    {
      float zi = red2[0][0][b][cl] + red2[1][0][b][cl] + red2[2][0][b][cl] + red2[3][0][b][cl] + bf2f(z0p);
      float zf = red2[0][1][b][cl] + red2[1][1][b][cl] + red2[2][1][b][cl] + red2[3][1][b][cl] + bf2f(z1p);
      float zo = red2[0][2][b][cl] + red2[1][2][b][cl] + red2[2][2][b][cl] + red2[3][2][b][cl] + bf2f(z2p);
      float zu = red2[0][3][b][cl] + red2[1][3][b][cl] + red2[2][3][b][cl] + red2[3][3][b][cl] + bf2f(z3p);
      float ig = sigm(zi), fg = sigm(zf), og = sigm(zo), ug = tanh_f(zu);
      c = fg * c + ig * ug;
      float h = og * tanh_f(c);
      short hb = f2bf(h);
      htile[b][cl] = hb;
      hs[rrow * H_ + colg + cl] = hb;   // plain store; consumed after kernel end
    }
    __syncthreads();
    if (tid < 64) {            // wave 0: stores + drain + flag
      int b2 = tid >> 2, ch = tid & 3;
      ull v = *(const ull*)&htile[b2][ch << 2];
      __hip_atomic_store(&h_prev[b2 * 256 + (colg >> 2) + ch], v,
                         __ATOMIC_RELAXED, __HIP_MEMORY_SCOPE_AGENT);
      __builtin_amdgcn_s_waitcnt(0);
      if (tid == 0)
        __hip_atomic_store(&flags_h[g << 5], (unsigned)(t + 1),
                           __ATOMIC_RELAXED, __HIP_MEMORY_SCOPE_AGENT);
    }
  }
}

// ---------------------------------------------------------------------------
__global__ __launch_bounds__(256) void reduce_nll(const float* __restrict__ se,
                                                  const float* __restrict__ ly,
                                                  float* __restrict__ out) {
  __shared__ float buf[256];
  float s = 0.f;
  for (int r = threadIdx.x; r < BT_; r += 256)
    s += logf(se[r]) - ly[r];
  buf[threadIdx.x] = s;
  __syncthreads();
  for (int off = 128; off > 0; off >>= 1) {
    if (threadIdx.x < off) buf[threadIdx.x] += buf[threadIdx.x + off];
    __syncthreads();
  }
  if (threadIdx.x == 0) out[0] = buf[0] * (1.0f / BT_);
}

// ---------------------------------------------------------------------------
extern "C" void kernel_launch(void* const* d_in, const int* in_sizes, int n_in,
                              void* d_out, int out_size, void* d_ws, size_t ws_size,
                              hipStream_t stream) {
  const int*   xs     = (const int*)d_in[0];
  const int*   ys     = (const int*)d_in[1];
  const float* embw   = (const float*)d_in[2];
  const float* wx     = (const float*)d_in[3];
  const float* wh     = (const float*)d_in[4];
  const float* wmx    = (const float*)d_in[5];
  const float* wmh    = (const float*)d_in[6];
  const float* bias   = (const float*)d_in[7];
  const float* gx     = (const float*)d_in[8];
  const float* gh     = (const float*)d_in[9];
  const float* gmx    = (const float*)d_in[10];
  const float* gmh    = (const float*)d_in[11];
  const float* pred_w = (const float*)d_in[12];
  const float* pred_b = (const float*)d_in[13];
  float* out = (float*)d_out;

  char* base = (char*)d_ws;
  size_t off = 0;
  auto alloc = [&](size_t bytes) -> void* {
    void* p = base + off;
    off = (off + bytes + 255) & ~(size_t)255;
    return p;
  };
  short* xb     = (short*)alloc((size_t)BT_ * E_ * 2);   //  8 MB
  short* zxb    = (short*)alloc((size_t)BT_ * H4_ * 2);  // 64 MB
  short* mxb    = (short*)alloc((size_t)BT_ * H_ * 2);   // 16 MB
  short* hs     = (short*)alloc((size_t)BT_ * H_ * 2);   // 16 MB
  short* wxT    = (short*)alloc((size_t)H4_ * E_ * 2);   //  4 MB
  short* whT    = (short*)alloc((size_t)H4_ * H_ * 2);   //  8 MB
  short* wmxT   = (short*)alloc((size_t)H_ * E_ * 2);    //  1 MB
  short* wmhT   = (short*)alloc((size_t)H_ * H_ * 2);    //  2 MB
  short* pwb    = (short*)alloc((size_t)V_ * H_ * 2);    // 16 MB
  float* scx    = (float*)alloc(H4_ * 4);
  float* sch    = (float*)alloc(H4_ * 4);
  float* scmx   = (float*)alloc(H_ * 4);
  float* scmh   = (float*)alloc(H_ * 4);
  float* l_y    = (float*)alloc(BT_ * 4);
  ull*   m_buf  = (ull*)alloc(B_ * H_ * 2);              // no init needed
  // ---- zero zone (one memset covers all of these) ----
  size_t z0 = off;
  float*    sumexp  = (float*)alloc(BT_ * 4);
  unsigned* flags_m = (unsigned*)alloc(NWG_ * 32 * 4);   // 8 KB
  unsigned* flags_h = (unsigned*)alloc(NWG_ * 32 * 4);   // 8 KB
  ull*      h_prev  = (ull*)alloc(B_ * H_ * 2);          // 32 KB
  size_t zlen = off - z0;

  hipMemsetAsync(base + z0, 0, zlen, stream);

  // weight norm -> transposed bf16 copies
  colscale<<<H4_ / 256, 256, 0, stream>>>(wx, gx, scx, E_, H4_);
  colscale<<<H4_ / 256, 256, 0, stream>>>(wh, gh, sch, H_, H4_);
  colscale<<<H_ / 256, 256, 0, stream>>>(wmx, gmx, scmx, E_, H_);
  colscale<<<H_ / 256, 256, 0, stream>>>(wmh, gmh, scmh, H_, H_);
  transpose_cast<<<(E_ / 32) * (H4_ / 32), 256, 0, stream>>>(wx, scx, wxT, E_, H4_);
  transpose_cast<<<(H_ / 32) * (H4_ / 32), 256, 0, stream>>>(wh, sch, whT, H_, H4_);
  transpose_cast<<<(E_ / 32) * (H_ / 32), 256, 0, stream>>>(wmx, scmx, wmxT, E_, H_);
  transpose_cast<<<(H_ / 32) * (H_ / 32), 256, 0, stream>>>(wmh, scmh, wmhT, H_, H_);
  castbf<<<((long)V_ * H_) / 1024, 256, 0, stream>>>(pred_w, pwb, (long)V_ * H_);

  // embed + input-dependent projections
  embed_gather<<<BT_, 256, 0, stream>>>(xs, embw, xb);
  gemm_bt<<<(BT_ / 128) * (H4_ / 128), 256, 0, stream>>>(xb, wxT, bias, zxb, BT_, H4_, E_);
  gemm_bt<<<(BT_ / 128) * (H_ / 128), 256, 0, stream>>>(xb, wmxT, nullptr, mxb, BT_, H_, E_);

  // sequential mLSTM scan (persistent, batched LIC exchange, flag barrier)
  scan_kernel<<<NWG_, 256, 0, stream>>>(zxb, mxb, wmhT, whT, hs,
                                        h_prev, m_buf, flags_m, flags_h);

  // fused logits + exp-sum + target logit, then mean NLL
  gemm_logits<<<(BT_ / 128) * (V_ / 128), 256, 0, stream>>>(hs, pwb, pred_b, ys,
                                                            sumexp, l_y, BT_, V_, H_);
  reduce_nll<<<1, 256, 0, stream>>>(sumexp, l_y, out);
}